// Round 4
// baseline (340.176 us; speedup 1.0000x reference)
//
#include <hip/hip_runtime.h>

// Shapes (fixed by the reference): B=4096, V=64, DI=DO=128. All I/O f32.
#define BN 4096
#define VN 64
#define DI 128
#define DO 128

typedef __attribute__((ext_vector_type(8))) short short8;
typedef __attribute__((ext_vector_type(4))) float f32x4;

__device__ __forceinline__ float bf2f(unsigned short s) {
    return __uint_as_float(((unsigned)s) << 16);
}
__device__ __forceinline__ unsigned short f2bf(float f) {   // RNE
    unsigned u = __float_as_uint(f);
    u += 0x7FFF + ((u >> 16) & 1);
    return (unsigned short)(u >> 16);
}
// trunc pack (A-inputs only; h uses RNE)
__device__ __forceinline__ unsigned pack_bf16_trunc(float lo, float hi) {
    return __builtin_amdgcn_perm(__float_as_uint(hi), __float_as_uint(lo), 0x07060302u);
}
__device__ __forceinline__ unsigned pack_bf16_rne(float lo, float hi) {
    return (unsigned)f2bf(lo) | ((unsigned)f2bf(hi) << 16);
}

// h is stored in MFMA C-fragment layout (bf16 units):
//   Hoff(bt,v,w,nt,rt,lane,e) = (((((bt*64+v)*4+w)*4+nt)*4+rt)*64 + lane)*4 + e
// Row b = bt*128+wm*64+rt*16+quad*4+e, col o = wn*64+nt*16+l16, w=wm*2+wn,
// lane=quad*16+l16. k_mix reads this layout — it must not change.

// ---------------------------------------------------------------------------
// Kernel 0: prep. Blocks 0..511: transpose W[v] f32 -> Wt[v] (DOxDI bf16).
// Block 512: adj f32 -> adjbf bf16.
// ---------------------------------------------------------------------------
__global__ __launch_bounds__(256) void k_prep(const float* __restrict__ W,
                                              const float* __restrict__ adj,
                                              unsigned short* __restrict__ Wt,
                                              unsigned short* __restrict__ adjbf) {
    const int t = threadIdx.x, blk = blockIdx.x;
    if (blk < 512) {
        const int v = blk >> 3, q = blk & 7;
        const float* Wv = W + (size_t)v * DI * DO;
        unsigned short* Wtv = Wt + (size_t)v * DI * DO;
        const int o = t & 127;
        const int i0 = q * 16 + (t >> 7) * 8;
        short8 s0;
#pragma unroll
        for (int j = 0; j < 8; ++j)
            s0[j] = (short)f2bf(Wv[(size_t)(i0 + j) * DO + o]);
        *(short8*)(Wtv + o * DI + i0) = s0;
    } else {
        short8 s0, s1;
#pragma unroll
        for (int j = 0; j < 8; ++j) s0[j] = (short)f2bf(adj[t * 16 + j]);
#pragma unroll
        for (int j = 0; j < 8; ++j) s1[j] = (short)f2bf(adj[t * 16 + 8 + j]);
        *(short8*)(adjbf + t * 16) = s0;
        *(short8*)(adjbf + t * 16 + 8) = s1;
    }
}

// ---------------------------------------------------------------------------
// Kernel 1: grouped GEMM h = feat @ W[v] + b[v], bf16 MFMA.
// R4 geometry change: tile = 16 rows x 8 CONSECUTIVE v (was 128 rows x 1 v).
// Evidence: three structurally different gemm1s all stuck at 1.7-1.9 TB/s
// while k_mix moves similar bytes at 4.5 TB/s. Common factor was the feat
// read comb: 512 B per DRAM page touch (rows at 32 KB stride) -> DRAM
// activate-rate-bound at ~30% of peak. Now each row contributes 4 KB
// CONTIGUOUS (8 v x 512 B) per touch. LDS 64 KB [row][vi][chunk] staged by
// global_load_lds (linear dest, XOR-chunk swizzle applied on SOURCE addr,
// un-XORed on ds_read). 2 blocks/CU -> stage/compute overlap via the other
// resident block. Wave w owns v-pair {2w, 2w+1}; per-v epilogue writes the
// SAME h fragment layout as before (rt fixed per block). BN partials now
// per-16-row-group: psA/psB = 64*256*128 f32 (8 MB each).
// ---------------------------------------------------------------------------
__global__ __launch_bounds__(256) void k_gemm1(const float* __restrict__ feat,
                                               const unsigned short* __restrict__ Wt,
                                               const float* __restrict__ bias,
                                               unsigned short* __restrict__ h,
                                               float* __restrict__ psA,
                                               float* __restrict__ psB) {
    __shared__ float ldsA[16 * 8 * 128];   // 64 KB: [row][vi][128] (chunk-swizzled)
    const int vg = blockIdx.x;             // v-group: v = vg*8 + vi
    const int rg = blockIdx.y;             // 16-row group: rows [rg*16, rg*16+16)
    const int tid = threadIdx.x;
    const int w = tid >> 6, lane = tid & 63;
    const int quad = lane >> 4, l16 = lane & 15;

    // --- stage: wave w stages rows [w*4, w*4+4); 4 x 1KB instrs per row ---
    // Per instr: lane l -> vi = q*2 + (l>>5), 16B-chunk pos p = l&31 within
    // the 512B v-slab. Position p holds global chunk p ^ (row&7).
    {
        const int vi2 = lane >> 5;          // 0..1
        const int cpos = lane & 31;         // chunk position in 512B slab
#pragma unroll
        for (int r = 0; r < 4; ++r) {
            const int row = w * 4 + r;
            const int gc = cpos ^ (row & 7);
#pragma unroll
            for (int q = 0; q < 4; ++q) {
                const float* src = feat + (size_t)(rg * 16 + row) * (VN * DI)
                                 + (vg * 8 + q * 2 + vi2) * DI + gc * 4;
                float* dst = &ldsA[(row * 8 + q * 2) * 128];
                __builtin_amdgcn_global_load_lds(
                    (const __attribute__((address_space(1))) void*)src,
                    (__attribute__((address_space(3))) void*)dst, 16, 0, 0);
            }
        }
    }
    __syncthreads();   // vmcnt(0) drain: whole 64 KB tile resident

    const int bt = rg >> 3, wm = (rg >> 2) & 1, rt = rg & 3;

#pragma unroll
    for (int vv = 0; vv < 2; ++vv) {
        const int vi = w * 2 + vv;
        const int v = vg * 8 + vi;

        // A fragments: row = l16, k = ks*32 + quad*8 + j
        short8 aF[4];
#pragma unroll
        for (int ks = 0; ks < 4; ++ks) {
            const int xr = l16 & 7;
            const int c0 = ks * 8 + quad * 2;
            const f32x4 f0 = *(const f32x4*)&ldsA[(l16 * 8 + vi) * 128 + ((c0    ) ^ xr) * 4];
            const f32x4 f1 = *(const f32x4*)&ldsA[(l16 * 8 + vi) * 128 + ((c0 + 1) ^ xr) * 4];
            union { short8 s; unsigned u[4]; } pk;
            pk.u[0] = pack_bf16_trunc(f0[0], f0[1]);
            pk.u[1] = pack_bf16_trunc(f0[2], f0[3]);
            pk.u[2] = pack_bf16_trunc(f1[0], f1[1]);
            pk.u[3] = pack_bf16_trunc(f1[2], f1[3]);
            aF[ks] = pk.s;
        }

        f32x4 acc[8];
#pragma unroll
        for (int j = 0; j < 8; ++j) acc[j] = (f32x4){0.f, 0.f, 0.f, 0.f};

        // B fragments from L2-hot Wt[v], reloaded per K-slice (8 live regs x4)
        const unsigned short* wb = Wt + (size_t)v * (DI * DO)
                                 + (size_t)l16 * DI + quad * 8;
#pragma unroll
        for (int ks = 0; ks < 4; ++ks) {
            short8 bb[8];
#pragma unroll
            for (int j = 0; j < 8; ++j)
                bb[j] = *(const short8*)(wb + j * (16 * DI) + ks * 32);
#pragma unroll
            for (int j = 0; j < 8; ++j)
                acc[j] = __builtin_amdgcn_mfma_f32_16x16x32_bf16(
                    aF[ks], bb[j], acc[j], 0, 0, 0);
        }

        // epilogue for this v: +bias, BN partials, fragment-layout h stores
        unsigned short* hbase = h + ((size_t)(bt * 64 + v) * 4 + wm * 2) * 4096;
#pragma unroll
        for (int j = 0; j < 8; ++j) {
            const int col = j * 16 + l16;
            const float bv = bias[v * DO + col];
            float s = 0.f, sq = 0.f;
#pragma unroll
            for (int e = 0; e < 4; ++e) {
                float x = acc[j][e] + bv;
                acc[j][e] = x;
                s += x;
                sq += x * x;
            }
            s += __shfl_down(s, 32);  s += __shfl_down(s, 16);
            sq += __shfl_down(sq, 32); sq += __shfl_down(sq, 16);
            if (lane < 16) {
                const size_t pi = ((size_t)v * 256 + rg) * 128 + col;
                psA[pi] = s;
                psB[pi] = sq;
            }
            uint2 pk;
            pk.x = pack_bf16_rne(acc[j][0], acc[j][1]);
            pk.y = pack_bf16_rne(acc[j][2], acc[j][3]);
            *(uint2*)(hbase + (size_t)(j >> 2) * 4096
                      + (size_t)(((j & 3) * 4 + rt) * 64 + lane) * 4) = pk;
        }
    }
}

// ---------------------------------------------------------------------------
// Kernel 2a: reduce partials -> scale, shift. 64 blocks (v). 256 groups now.
// ---------------------------------------------------------------------------
__global__ __launch_bounds__(128) void k_reduce(const float* __restrict__ psA,
                                                const float* __restrict__ psB,
                                                const float* __restrict__ gamma,
                                                const float* __restrict__ beta,
                                                float* __restrict__ scale,
                                                float* __restrict__ shift) {
    const int o = threadIdx.x;
    const int v = blockIdx.x;
    float s = 0.f, sq = 0.f;
#pragma unroll 8
    for (int p = 0; p < 256; ++p) {
        const size_t pi = ((size_t)v * 256 + p) * 128 + o;
        s += psA[pi];
        sq += psB[pi];
    }
    const float invB = 1.0f / (float)BN;
    const float mu = s * invB;
    const float var = sq * invB - mu * mu;
    const float sc = gamma[v * DO + o] * rsqrtf(var + 1e-5f);
    scale[v * DO + o] = sc;
    shift[v * DO + o] = beta[v * DO + o] - mu * sc;
}

// ---------------------------------------------------------------------------
// Kernel 2b: C0[u,o] = sum_v adj[u,v] * shift[v,o]. 64 blocks (u).
// ---------------------------------------------------------------------------
__global__ __launch_bounds__(128) void k_c0(const float* __restrict__ adj,
                                            const float* __restrict__ shift,
                                            float* __restrict__ C0) {
    const int o = threadIdx.x;
    const int u = blockIdx.x;
    float c0 = 0.f;
#pragma unroll
    for (int v = 0; v < VN; ++v)
        c0 += adj[u * VN + v] * shift[v * DO + o];
    C0[u * DO + o] = c0;
}

// ---------------------------------------------------------------------------
// Kernel 3 (MFMA mix): out[b,u,o] = relu( sum_v adj[u,v]*(h[b,v,o]*scale[v,o])
//                                         + C0[u,o] )
// Known-good R0/R1 version (R2's rewrite regressed; reverted in R3).
// Runs at ~4.5 TB/s effective — near mixed-rw ceiling. Unchanged.
// ---------------------------------------------------------------------------
__global__ __launch_bounds__(512, 4) void k_mix(const unsigned short* __restrict__ h,
                                                const float* __restrict__ scale,
                                                const unsigned short* __restrict__ adjbf,
                                                const float* __restrict__ C0,
                                                float* __restrict__ out) {
    __shared__ unsigned short hsT[4][DO][72];   // 73,728 B
    const int t = threadIdx.x;
    const int b0 = blockIdx.x * 4;
    const int bt = b0 >> 7;
    const int r = b0 & 127;
    const int swm = r >> 6, srt = (r >> 4) & 3, squad = (r >> 2) & 3;

    // stage: 16 iters x 512 threads = 8192 (v,o) pairs, 8 B each
#pragma unroll
    for (int c = 0; c < 16; ++c) {
        const int p = c * 512 + t;
        const int v = p >> 7, o = p & 127;
        const size_t off = (size_t)(bt * 64 + v) * 16384
                         + (size_t)(((swm * 2 + (o >> 6)) * 4 + ((o >> 4) & 3)) * 4 + srt) * 256
                         + (size_t)(squad * 16 + (o & 15)) * 4;
        const uint2 pk = *(const uint2*)(h + off);
        const float sc = scale[v * DO + o];
        hsT[0][o][v] = f2bf(bf2f((unsigned short)(pk.x & 0xFFFF)) * sc);
        hsT[1][o][v] = f2bf(bf2f((unsigned short)(pk.x >> 16)) * sc);
        hsT[2][o][v] = f2bf(bf2f((unsigned short)(pk.y & 0xFFFF)) * sc);
        hsT[3][o][v] = f2bf(bf2f((unsigned short)(pk.y >> 16)) * sc);
    }
    __syncthreads();

    const int w = t >> 6, lane = t & 63;
    const int bl = w >> 1, nh = w & 1;
    const int quad = lane >> 4, l16 = lane & 15;
    const int b = b0 + bl;

    short8 af[4][2];
#pragma unroll
    for (int mt = 0; mt < 4; ++mt)
#pragma unroll
        for (int ks = 0; ks < 2; ++ks)
            af[mt][ks] = *(const short8*)(adjbf + (mt * 16 + l16) * VN
                                          + ks * 32 + quad * 8);

    f32x4 acc[4][4];
#pragma unroll
    for (int mt = 0; mt < 4; ++mt)
#pragma unroll
        for (int nt = 0; nt < 4; ++nt) acc[mt][nt] = (f32x4){0.f, 0.f, 0.f, 0.f};

#pragma unroll
    for (int nt = 0; nt < 4; ++nt) {
        const unsigned short* bp = &hsT[bl][nh * 64 + nt * 16 + l16][quad * 8];
        short8 bf0 = *(const short8*)(bp);
        short8 bf1 = *(const short8*)(bp + 32);
#pragma unroll
        for (int mt = 0; mt < 4; ++mt) {
            acc[mt][nt] = __builtin_amdgcn_mfma_f32_16x16x32_bf16(
                af[mt][0], bf0, acc[mt][nt], 0, 0, 0);
            acc[mt][nt] = __builtin_amdgcn_mfma_f32_16x16x32_bf16(
                af[mt][1], bf1, acc[mt][nt], 0, 0, 0);
        }
    }

#pragma unroll
    for (int mt = 0; mt < 4; ++mt)
#pragma unroll
        for (int nt = 0; nt < 4; ++nt) {
            const int o = nh * 64 + nt * 16 + l16;
#pragma unroll
            for (int e = 0; e < 4; ++e) {
                const int u = mt * 16 + quad * 4 + e;
                out[((size_t)b * VN + u) * DO + o] =
                    fmaxf(acc[mt][nt][e] + C0[u * DO + o], 0.0f);
            }
        }
}

// ---------------------------------------------------------------------------
extern "C" void kernel_launch(void* const* d_in, const int* in_sizes, int n_in,
                              void* d_out, int out_size, void* d_ws, size_t ws_size,
                              hipStream_t stream) {
    const float* feat  = (const float*)d_in[0];
    const float* adj   = (const float*)d_in[1];
    const float* W     = (const float*)d_in[2];
    const float* bias  = (const float*)d_in[3];
    const float* gamma = (const float*)d_in[4];
    const float* beta  = (const float*)d_in[5];
    float* out = (float*)d_out;

    char* ws = (char*)d_ws;
    unsigned short* h     = (unsigned short*)ws;                 // 67,108,864 B
    unsigned short* Wt    = (unsigned short*)(ws + 67108864ull); //  2,097,152 B
    unsigned short* adjbf = (unsigned short*)(ws + 69206016ull); //      8,192 B
    float* psA   = (float*)(ws + 69214208ull);                   //  8 MiB
    float* psB   = psA + 2097152;                                //  8 MiB
    float* scale = psB + 2097152;                                // 32 KiB
    float* shift = scale + 8192;                                 // 32 KiB
    float* C0    = shift + 8192;                                 // 32 KiB

    k_prep<<<dim3(513), dim3(256), 0, stream>>>(W, adj, Wt, adjbf);
    k_gemm1<<<dim3(8, 256), dim3(256), 0, stream>>>(feat, Wt, bias, h, psA, psB);
    k_reduce<<<dim3(64), dim3(128), 0, stream>>>(psA, psB, gamma, beta, scale, shift);
    k_c0<<<dim3(64), dim3(128), 0, stream>>>(adj, shift, C0);
    k_mix<<<dim3(1024), dim3(512), 0, stream>>>(h, scale, adjbf, C0, out);
}

// Round 5
// 287.917 us; speedup vs baseline: 1.1815x; 1.1815x over previous
//
#include <hip/hip_runtime.h>

// Shapes (fixed by the reference): B=4096, V=64, DI=DO=128. All I/O f32.
#define BN 4096
#define VN 64
#define DI 128
#define DO 128

typedef __attribute__((ext_vector_type(8))) short short8;
typedef __attribute__((ext_vector_type(4))) float f32x4;

__device__ __forceinline__ float bf2f(unsigned short s) {
    return __uint_as_float(((unsigned)s) << 16);
}
__device__ __forceinline__ unsigned short f2bf(float f) {   // RNE
    unsigned u = __float_as_uint(f);
    u += 0x7FFF + ((u >> 16) & 1);
    return (unsigned short)(u >> 16);
}
// trunc pack (A-inputs only; h uses RNE)
__device__ __forceinline__ unsigned pack_bf16_trunc(float lo, float hi) {
    return __builtin_amdgcn_perm(__float_as_uint(hi), __float_as_uint(lo), 0x07060302u);
}
__device__ __forceinline__ unsigned pack_bf16_rne(float lo, float hi) {
    return (unsigned)f2bf(lo) | ((unsigned)f2bf(hi) << 16);
}

// h is stored in MFMA C-fragment layout (bf16 units):
//   Hoff(bt,v,w,nt,rt,lane,e) = (((((bt*64+v)*4+w)*4+nt)*4+rt)*64 + lane)*4 + e
// Row b = bt*128+wm*64+rt*16+quad*4+e, col o = wn*64+nt*16+l16, w=wm*2+wn,
// lane=quad*16+l16. k_mix reads this layout — unchanged since R0.

// ---------------------------------------------------------------------------
// Kernel 0: prep. Blocks 0..511: transpose W[v] f32 -> Wt[v] (DOxDI bf16).
// Block 512: adj f32 -> adjbf bf16.
// ---------------------------------------------------------------------------
__global__ __launch_bounds__(256) void k_prep(const float* __restrict__ W,
                                              const float* __restrict__ adj,
                                              unsigned short* __restrict__ Wt,
                                              unsigned short* __restrict__ adjbf) {
    const int t = threadIdx.x, blk = blockIdx.x;
    if (blk < 512) {
        const int v = blk >> 3, q = blk & 7;
        const float* Wv = W + (size_t)v * DI * DO;
        unsigned short* Wtv = Wt + (size_t)v * DI * DO;
        const int o = t & 127;
        const int i0 = q * 16 + (t >> 7) * 8;
        short8 s0;
#pragma unroll
        for (int j = 0; j < 8; ++j)
            s0[j] = (short)f2bf(Wv[(size_t)(i0 + j) * DO + o]);
        *(short8*)(Wtv + o * DI + i0) = s0;
    } else {
        short8 s0, s1;
#pragma unroll
        for (int j = 0; j < 8; ++j) s0[j] = (short)f2bf(adj[t * 16 + j]);
#pragma unroll
        for (int j = 0; j < 8; ++j) s1[j] = (short)f2bf(adj[t * 16 + 8 + j]);
        *(short8*)(adjbf + t * 16) = s0;
        *(short8*)(adjbf + t * 16 + 8) = s1;
    }
}

// ---------------------------------------------------------------------------
// Kernel 1: grouped GEMM h = feat @ W[v] + b[v], 128x128 tile, bf16 MFMA.
// R5: BARRIER-FREE wave-private staging. Evidence R0-R4: all structures with
// a block-wide drain stuck at 1.3-1.9 TB/s; R4's contiguity "fix" regressed
// -> limiter is HBM issue DUTY CYCLE (whole block idles in vmcnt(0) drain,
// issues nothing during compute; phases of the 2 resident blocks align).
// Now: wave w only reads rows wm*64..+63, so each wave DMAs its OWN 64 rows
// (32 x global_load_lds; wave pairs duplicate-write identical bytes — benign,
// dup fetch = L2 hit), then waits vmcnt(0) on ITS OWN loads + sched_barrier
// (rule #18) and computes. NO __syncthreads: 8 waves/CU in self-timed loops
// keep loads in flight continuously. Everything else = R3/R1 known-good
// (bb[4][4] up-front, contiguous 32KB h slab, 2MB BN partials).
// ---------------------------------------------------------------------------
__global__ __launch_bounds__(256) void k_gemm1(const float* __restrict__ feat,
                                               const unsigned short* __restrict__ Wt,
                                               const float* __restrict__ bias,
                                               unsigned short* __restrict__ h,
                                               float* __restrict__ psA,
                                               float* __restrict__ psB) {
    __shared__ float ldsA[128 * 128];   // 64 KB feat tile (chunk-swizzled rows)
    const int v = blockIdx.x;
    const int bt = blockIdx.y;
    const int tid = threadIdx.x;
    const int w = tid >> 6, lane = tid & 63;
    const int wm = w >> 1, wn = w & 1;
    const int quad = lane >> 4, l16 = lane & 15;

    // --- stage: wave w DMAs rows [wm*64, wm*64+64) — everything it reads ---
    // One instr = 1 KB = 2 rows (lane>>5 picks row parity, lane&31 = 16B-chunk
    // position p; position p of row r holds global chunk p ^ (r&7)).
    {
        const int lrow = lane >> 5;          // 0..1
        const int lpos = lane & 31;          // chunk position 0..31
#pragma unroll
        for (int i = 0; i < 32; ++i) {
            const int row = wm * 64 + 2 * i + lrow;
            const int gchunk = lpos ^ (row & 7);
            const float* src = feat + (size_t)(bt * 128 + row) * (VN * DI)
                             + v * DI + gchunk * 4;
            float* dst = &ldsA[(wm * 64 + 2 * i) * 128];
            __builtin_amdgcn_global_load_lds(
                (const __attribute__((address_space(1))) void*)src,
                (__attribute__((address_space(3))) void*)dst, 16, 0, 0);
        }
    }

    // --- B fragments up-front (L2-hot: XCD = v%8 for all bt) ---
    const unsigned short* wbase = Wt + (size_t)v * (DI * DO)
                                + (size_t)(wn * 64 + l16) * DI + quad * 8;
    short8 bb[4][4];
#pragma unroll
    for (int ks = 0; ks < 4; ++ks)
#pragma unroll
        for (int nt = 0; nt < 4; ++nt)
            bb[ks][nt] = *(const short8*)(wbase + nt * (16 * DI) + ks * 32);

    // per-wave drain of its OWN DMA (+bb); no cross-wave barrier needed —
    // this wave staged every row it reads. sched_barrier stops hipcc from
    // hoisting the dependent ds_reads above the wait (rule #18).
    asm volatile("s_waitcnt vmcnt(0)" ::: "memory");
    __builtin_amdgcn_sched_barrier(0);

    f32x4 acc[4][4];
#pragma unroll
    for (int rt = 0; rt < 4; ++rt)
#pragma unroll
        for (int nt = 0; nt < 4; ++nt) acc[rt][nt] = (f32x4){0.f, 0.f, 0.f, 0.f};

#pragma unroll
    for (int ks = 0; ks < 4; ++ks) {
        short8 aCur[4];
#pragma unroll
        for (int rt = 0; rt < 4; ++rt) {
            const int row = wm * 64 + rt * 16 + l16;
            const int xr = row & 7;
            const int c0 = ks * 8 + quad * 2;
            const f32x4 f0 = *(const f32x4*)&ldsA[row * 128 + ((c0    ) ^ xr) * 4];
            const f32x4 f1 = *(const f32x4*)&ldsA[row * 128 + ((c0 + 1) ^ xr) * 4];
            union { short8 s; unsigned u[4]; } pk;
            pk.u[0] = pack_bf16_trunc(f0[0], f0[1]);
            pk.u[1] = pack_bf16_trunc(f0[2], f0[3]);
            pk.u[2] = pack_bf16_trunc(f1[0], f1[1]);
            pk.u[3] = pack_bf16_trunc(f1[2], f1[3]);
            aCur[rt] = pk.s;
        }
#pragma unroll
        for (int rt = 0; rt < 4; ++rt)
#pragma unroll
            for (int nt = 0; nt < 4; ++nt)
                acc[rt][nt] = __builtin_amdgcn_mfma_f32_16x16x32_bf16(
                    aCur[rt], bb[ks][nt], acc[rt][nt], 0, 0, 0);
    }

    // epilogue: +bias, BN partials (race-free), fragment-layout h stores
    unsigned short* hblk = h + ((size_t)(bt * 64 + v) * 4 + w) * 4096;
#pragma unroll
    for (int nt = 0; nt < 4; ++nt) {
        const int col = wn * 64 + nt * 16 + l16;
        const float bv = bias[v * DO + col];
        float s = 0.f, sq = 0.f;
#pragma unroll
        for (int rt = 0; rt < 4; ++rt)
#pragma unroll
            for (int e = 0; e < 4; ++e) {
                float x = acc[rt][nt][e] + bv;
                acc[rt][nt][e] = x;
                s += x;
                sq += x * x;
            }
        s += __shfl_down(s, 32);  s += __shfl_down(s, 16);
        sq += __shfl_down(sq, 32); sq += __shfl_down(sq, 16);
        if (lane < 16) {
            const size_t pi = ((size_t)(v * 32 + bt) * 2 + wm) * 128 + col;
            psA[pi] = s;
            psB[pi] = sq;
        }
#pragma unroll
        for (int rt = 0; rt < 4; ++rt) {
            uint2 pk;
            pk.x = pack_bf16_rne(acc[rt][nt][0], acc[rt][nt][1]);
            pk.y = pack_bf16_rne(acc[rt][nt][2], acc[rt][nt][3]);
            *(uint2*)(hblk + (size_t)((nt * 4 + rt) * 64 + lane) * 4) = pk;
        }
    }
}

// ---------------------------------------------------------------------------
// Kernel 2a: reduce partials -> scale, shift. 64 blocks (v).
// ---------------------------------------------------------------------------
__global__ __launch_bounds__(128) void k_reduce(const float* __restrict__ psA,
                                                const float* __restrict__ psB,
                                                const float* __restrict__ gamma,
                                                const float* __restrict__ beta,
                                                float* __restrict__ scale,
                                                float* __restrict__ shift) {
    const int o = threadIdx.x;
    const int v = blockIdx.x;
    float s = 0.f, sq = 0.f;
#pragma unroll
    for (int p = 0; p < 64; ++p) {
        const size_t pi = ((size_t)v * 64 + p) * 128 + o;
        s += psA[pi];
        sq += psB[pi];
    }
    const float invB = 1.0f / (float)BN;
    const float mu = s * invB;
    const float var = sq * invB - mu * mu;
    const float sc = gamma[v * DO + o] * rsqrtf(var + 1e-5f);
    scale[v * DO + o] = sc;
    shift[v * DO + o] = beta[v * DO + o] - mu * sc;
}

// ---------------------------------------------------------------------------
// Kernel 2b: C0[u,o] = sum_v adj[u,v] * shift[v,o]. 64 blocks (u).
// ---------------------------------------------------------------------------
__global__ __launch_bounds__(128) void k_c0(const float* __restrict__ adj,
                                            const float* __restrict__ shift,
                                            float* __restrict__ C0) {
    const int o = threadIdx.x;
    const int u = blockIdx.x;
    float c0 = 0.f;
#pragma unroll
    for (int v = 0; v < VN; ++v)
        c0 += adj[u * VN + v] * shift[v * DO + o];
    C0[u * DO + o] = c0;
}

// ---------------------------------------------------------------------------
// Kernel 3 (MFMA mix): out[b,u,o] = relu( sum_v adj[u,v]*(h[b,v,o]*scale[v,o])
//                                         + C0[u,o] )
// Known-good R0/R1 version (~4.5 TB/s effective). Unchanged.
// ---------------------------------------------------------------------------
__global__ __launch_bounds__(512, 4) void k_mix(const unsigned short* __restrict__ h,
                                                const float* __restrict__ scale,
                                                const unsigned short* __restrict__ adjbf,
                                                const float* __restrict__ C0,
                                                float* __restrict__ out) {
    __shared__ unsigned short hsT[4][DO][72];   // 73,728 B
    const int t = threadIdx.x;
    const int b0 = blockIdx.x * 4;
    const int bt = b0 >> 7;
    const int r = b0 & 127;
    const int swm = r >> 6, srt = (r >> 4) & 3, squad = (r >> 2) & 3;

    // stage: 16 iters x 512 threads = 8192 (v,o) pairs, 8 B each
#pragma unroll
    for (int c = 0; c < 16; ++c) {
        const int p = c * 512 + t;
        const int v = p >> 7, o = p & 127;
        const size_t off = (size_t)(bt * 64 + v) * 16384
                         + (size_t)(((swm * 2 + (o >> 6)) * 4 + ((o >> 4) & 3)) * 4 + srt) * 256
                         + (size_t)(squad * 16 + (o & 15)) * 4;
        const uint2 pk = *(const uint2*)(h + off);
        const float sc = scale[v * DO + o];
        hsT[0][o][v] = f2bf(bf2f((unsigned short)(pk.x & 0xFFFF)) * sc);
        hsT[1][o][v] = f2bf(bf2f((unsigned short)(pk.x >> 16)) * sc);
        hsT[2][o][v] = f2bf(bf2f((unsigned short)(pk.y & 0xFFFF)) * sc);
        hsT[3][o][v] = f2bf(bf2f((unsigned short)(pk.y >> 16)) * sc);
    }
    __syncthreads();

    const int w = t >> 6, lane = t & 63;
    const int bl = w >> 1, nh = w & 1;
    const int quad = lane >> 4, l16 = lane & 15;
    const int b = b0 + bl;

    short8 af[4][2];
#pragma unroll
    for (int mt = 0; mt < 4; ++mt)
#pragma unroll
        for (int ks = 0; ks < 2; ++ks)
            af[mt][ks] = *(const short8*)(adjbf + (mt * 16 + l16) * VN
                                          + ks * 32 + quad * 8);

    f32x4 acc[4][4];
#pragma unroll
    for (int mt = 0; mt < 4; ++mt)
#pragma unroll
        for (int nt = 0; nt < 4; ++nt) acc[mt][nt] = (f32x4){0.f, 0.f, 0.f, 0.f};

#pragma unroll
    for (int nt = 0; nt < 4; ++nt) {
        const unsigned short* bp = &hsT[bl][nh * 64 + nt * 16 + l16][quad * 8];
        short8 bf0 = *(const short8*)(bp);
        short8 bf1 = *(const short8*)(bp + 32);
#pragma unroll
        for (int mt = 0; mt < 4; ++mt) {
            acc[mt][nt] = __builtin_amdgcn_mfma_f32_16x16x32_bf16(
                af[mt][0], bf0, acc[mt][nt], 0, 0, 0);
            acc[mt][nt] = __builtin_amdgcn_mfma_f32_16x16x32_bf16(
                af[mt][1], bf1, acc[mt][nt], 0, 0, 0);
        }
    }

#pragma unroll
    for (int mt = 0; mt < 4; ++mt)
#pragma unroll
        for (int nt = 0; nt < 4; ++nt) {
            const int o = nh * 64 + nt * 16 + l16;
#pragma unroll
            for (int e = 0; e < 4; ++e) {
                const int u = mt * 16 + quad * 4 + e;
                out[((size_t)b * VN + u) * DO + o] =
                    fmaxf(acc[mt][nt][e] + C0[u * DO + o], 0.0f);
            }
        }
}

// ---------------------------------------------------------------------------
extern "C" void kernel_launch(void* const* d_in, const int* in_sizes, int n_in,
                              void* d_out, int out_size, void* d_ws, size_t ws_size,
                              hipStream_t stream) {
    const float* feat  = (const float*)d_in[0];
    const float* adj   = (const float*)d_in[1];
    const float* W     = (const float*)d_in[2];
    const float* bias  = (const float*)d_in[3];
    const float* gamma = (const float*)d_in[4];
    const float* beta  = (const float*)d_in[5];
    float* out = (float*)d_out;

    char* ws = (char*)d_ws;
    unsigned short* h     = (unsigned short*)ws;                 // 67,108,864 B
    unsigned short* Wt    = (unsigned short*)(ws + 67108864ull); //  2,097,152 B
    unsigned short* adjbf = (unsigned short*)(ws + 69206016ull); //      8,192 B
    float* psA   = (float*)(ws + 69214208ull);                   //  2 MiB
    float* psB   = psA + 524288;                                 //  2 MiB
    float* scale = psB + 524288;                                 // 32 KiB
    float* shift = scale + 8192;                                 // 32 KiB
    float* C0    = shift + 8192;                                 // 32 KiB

    k_prep<<<dim3(513), dim3(256), 0, stream>>>(W, adj, Wt, adjbf);
    k_gemm1<<<dim3(64, 32), dim3(256), 0, stream>>>(feat, Wt, bias, h, psA, psB);
    k_reduce<<<dim3(64), dim3(128), 0, stream>>>(psA, psB, gamma, beta, scale, shift);
    k_c0<<<dim3(64), dim3(128), 0, stream>>>(adj, shift, C0);
    k_mix<<<dim3(1024), dim3(512), 0, stream>>>(h, scale, adjbf, C0, out);
}

// Round 6
// 285.179 us; speedup vs baseline: 1.1928x; 1.0096x over previous
//
#include <hip/hip_runtime.h>

// Shapes (fixed by the reference): B=4096, V=64, DI=DO=128. All I/O f32.
#define BN 4096
#define VN 64
#define DI 128
#define DO 128

typedef __attribute__((ext_vector_type(8))) short short8;
typedef __attribute__((ext_vector_type(4))) float f32x4;

__device__ __forceinline__ float bf2f(unsigned short s) {
    return __uint_as_float(((unsigned)s) << 16);
}
__device__ __forceinline__ unsigned short f2bf(float f) {   // RNE
    unsigned u = __float_as_uint(f);
    u += 0x7FFF + ((u >> 16) & 1);
    return (unsigned short)(u >> 16);
}
// trunc pack (A-inputs only; h uses RNE)
__device__ __forceinline__ unsigned pack_bf16_trunc(float lo, float hi) {
    return __builtin_amdgcn_perm(__float_as_uint(hi), __float_as_uint(lo), 0x07060302u);
}
__device__ __forceinline__ unsigned pack_bf16_rne(float lo, float hi) {
    return (unsigned)f2bf(lo) | ((unsigned)f2bf(hi) << 16);
}

// h is stored in MFMA C-fragment layout (bf16 units):
//   Hoff(bt,v,w,nt,rt,lane,e) = (((((bt*64+v)*4+w)*4+nt)*4+rt)*64 + lane)*4 + e
// Row b = bt*128+wm*64+rt*16+quad*4+e, col o = wn*64+nt*16+l16, w=wm*2+wn,
// lane=quad*16+l16. k_mix reads this layout — unchanged since R0.

// ---------------------------------------------------------------------------
// Kernel 0: prep. Blocks 0..511: transpose W[v] f32 -> Wt[v] (DOxDI bf16).
// Block 512: adj f32 -> adjbf bf16.
// ---------------------------------------------------------------------------
__global__ __launch_bounds__(256) void k_prep(const float* __restrict__ W,
                                              const float* __restrict__ adj,
                                              unsigned short* __restrict__ Wt,
                                              unsigned short* __restrict__ adjbf) {
    const int t = threadIdx.x, blk = blockIdx.x;
    if (blk < 512) {
        const int v = blk >> 3, q = blk & 7;
        const float* Wv = W + (size_t)v * DI * DO;
        unsigned short* Wtv = Wt + (size_t)v * DI * DO;
        const int o = t & 127;
        const int i0 = q * 16 + (t >> 7) * 8;
        short8 s0;
#pragma unroll
        for (int j = 0; j < 8; ++j)
            s0[j] = (short)f2bf(Wv[(size_t)(i0 + j) * DO + o]);
        *(short8*)(Wtv + o * DI + i0) = s0;
    } else {
        short8 s0, s1;
#pragma unroll
        for (int j = 0; j < 8; ++j) s0[j] = (short)f2bf(adj[t * 16 + j]);
#pragma unroll
        for (int j = 0; j < 8; ++j) s1[j] = (short)f2bf(adj[t * 16 + 8 + j]);
        *(short8*)(adjbf + t * 16) = s0;
        *(short8*)(adjbf + t * 16 + 8) = s1;
    }
}

// ---------------------------------------------------------------------------
// Kernel 1: grouped GEMM h = feat @ W[v] + b[v], 128x128 tile, bf16 MFMA.
// R6: COUNTED-vmcnt pipeline (T4) on top of R5's barrier-free wave-private
// staging. Evidence R0-R5: six structures, all 72-82 us, HBM 70-80% idle in
// gemm1's window, all pipes idle -> serialized latency exposure: every
// variant drained ALL staging (vmcnt(0)/__syncthreads) before MFMA #1.
// Now: issue 16 bb loads, then 32 DMA in 4 rt-ordered groups (SB-fenced),
// then per rt wait vmcnt(24-8*rt)+sched_barrier and compute — the last
// 24 KB of DMA latency hides under rt=0..2 compute. Wait ladder is
// insertion-proof (extra compiler loads only tighten the completed prefix).
// Accumulation order per acc[rt][nt] unchanged -> bit-identical results.
// ---------------------------------------------------------------------------
__global__ __launch_bounds__(256) void k_gemm1(const float* __restrict__ feat,
                                               const unsigned short* __restrict__ Wt,
                                               const float* __restrict__ bias,
                                               unsigned short* __restrict__ h,
                                               float* __restrict__ psA,
                                               float* __restrict__ psB) {
    __shared__ float ldsA[128 * 128];   // 64 KB feat tile (chunk-swizzled rows)
    const int v = blockIdx.x;
    const int bt = blockIdx.y;
    const int tid = threadIdx.x;
    const int w = tid >> 6, lane = tid & 63;
    const int wm = w >> 1, wn = w & 1;
    const int quad = lane >> 4, l16 = lane & 15;

    // --- (1) B fragments first (L2-hot: XCD = v%8 for all bt): 16 VMEM ---
    const unsigned short* wbase = Wt + (size_t)v * (DI * DO)
                                + (size_t)(wn * 64 + l16) * DI + quad * 8;
    short8 bb[4][4];
#pragma unroll
    for (int ks = 0; ks < 4; ++ks)
#pragma unroll
        for (int nt = 0; nt < 4; ++nt)
            bb[ks][nt] = *(const short8*)(wbase + nt * (16 * DI) + ks * 32);
    __builtin_amdgcn_sched_barrier(0);   // pin: bb issue before DMA

    // --- (2) DMA the wave's 64 rows in 4 rt-ordered groups of 8 x 1KB ---
    // lane l: row parity lrow=l>>5, chunk position p=l&31; position p of
    // row r holds global chunk p ^ (r&7) (read side XORs identically).
    // Wave pairs (same wm) duplicate-write identical bytes — benign.
    {
        const int lrow = lane >> 5;
        const int lpos = lane & 31;
#pragma unroll
        for (int g = 0; g < 4; ++g) {
#pragma unroll
            for (int i = 0; i < 8; ++i) {
                const int row = wm * 64 + g * 16 + 2 * i + lrow;
                const int gchunk = lpos ^ (row & 7);
                const float* src = feat + (size_t)(bt * 128 + row) * (VN * DI)
                                 + v * DI + gchunk * 4;
                float* dst = &ldsA[(wm * 64 + g * 16 + 2 * i) * 128];
                __builtin_amdgcn_global_load_lds(
                    (const __attribute__((address_space(1))) void*)src,
                    (__attribute__((address_space(3))) void*)dst, 16, 0, 0);
            }
            __builtin_amdgcn_sched_barrier(0);   // pin group order (vmcnt ladder)
        }
    }

    f32x4 acc[4][4];
#pragma unroll
    for (int rt = 0; rt < 4; ++rt)
#pragma unroll
        for (int nt = 0; nt < 4; ++nt) acc[rt][nt] = (f32x4){0.f, 0.f, 0.f, 0.f};

    // --- (3) compute, rt-outer: wait only for this rt's rows (+bb) ---
#pragma unroll
    for (int rt = 0; rt < 4; ++rt) {
        if (rt == 0)      asm volatile("s_waitcnt vmcnt(24)" ::: "memory");
        else if (rt == 1) asm volatile("s_waitcnt vmcnt(16)" ::: "memory");
        else if (rt == 2) asm volatile("s_waitcnt vmcnt(8)"  ::: "memory");
        else              asm volatile("s_waitcnt vmcnt(0)"  ::: "memory");
        __builtin_amdgcn_sched_barrier(0);   // rule #18: no hoist above wait

        const int row = wm * 64 + rt * 16 + l16;
        const int xr = row & 7;
        short8 aF[4];
#pragma unroll
        for (int ks = 0; ks < 4; ++ks) {
            const int c0 = ks * 8 + quad * 2;
            const f32x4 f0 = *(const f32x4*)&ldsA[row * 128 + ((c0    ) ^ xr) * 4];
            const f32x4 f1 = *(const f32x4*)&ldsA[row * 128 + ((c0 + 1) ^ xr) * 4];
            union { short8 s; unsigned u[4]; } pk;
            pk.u[0] = pack_bf16_trunc(f0[0], f0[1]);
            pk.u[1] = pack_bf16_trunc(f0[2], f0[3]);
            pk.u[2] = pack_bf16_trunc(f1[0], f1[1]);
            pk.u[3] = pack_bf16_trunc(f1[2], f1[3]);
            aF[ks] = pk.s;
        }
#pragma unroll
        for (int ks = 0; ks < 4; ++ks)
#pragma unroll
            for (int nt = 0; nt < 4; ++nt)
                acc[rt][nt] = __builtin_amdgcn_mfma_f32_16x16x32_bf16(
                    aF[ks], bb[ks][nt], acc[rt][nt], 0, 0, 0);
    }

    // epilogue: +bias, BN partials (race-free), fragment-layout h stores
    unsigned short* hblk = h + ((size_t)(bt * 64 + v) * 4 + w) * 4096;
#pragma unroll
    for (int nt = 0; nt < 4; ++nt) {
        const int col = wn * 64 + nt * 16 + l16;
        const float bv = bias[v * DO + col];
        float s = 0.f, sq = 0.f;
#pragma unroll
        for (int rt = 0; rt < 4; ++rt)
#pragma unroll
            for (int e = 0; e < 4; ++e) {
                float x = acc[rt][nt][e] + bv;
                acc[rt][nt][e] = x;
                s += x;
                sq += x * x;
            }
        s += __shfl_down(s, 32);  s += __shfl_down(s, 16);
        sq += __shfl_down(sq, 32); sq += __shfl_down(sq, 16);
        if (lane < 16) {
            const size_t pi = ((size_t)(v * 32 + bt) * 2 + wm) * 128 + col;
            psA[pi] = s;
            psB[pi] = sq;
        }
#pragma unroll
        for (int rt = 0; rt < 4; ++rt) {
            uint2 pk;
            pk.x = pack_bf16_rne(acc[rt][nt][0], acc[rt][nt][1]);
            pk.y = pack_bf16_rne(acc[rt][nt][2], acc[rt][nt][3]);
            *(uint2*)(hblk + (size_t)((nt * 4 + rt) * 64 + lane) * 4) = pk;
        }
    }
}

// ---------------------------------------------------------------------------
// Kernel 2a: reduce partials -> scale, shift. 64 blocks (v).
// ---------------------------------------------------------------------------
__global__ __launch_bounds__(128) void k_reduce(const float* __restrict__ psA,
                                                const float* __restrict__ psB,
                                                const float* __restrict__ gamma,
                                                const float* __restrict__ beta,
                                                float* __restrict__ scale,
                                                float* __restrict__ shift) {
    const int o = threadIdx.x;
    const int v = blockIdx.x;
    float s = 0.f, sq = 0.f;
#pragma unroll
    for (int p = 0; p < 64; ++p) {
        const size_t pi = ((size_t)v * 64 + p) * 128 + o;
        s += psA[pi];
        sq += psB[pi];
    }
    const float invB = 1.0f / (float)BN;
    const float mu = s * invB;
    const float var = sq * invB - mu * mu;
    const float sc = gamma[v * DO + o] * rsqrtf(var + 1e-5f);
    scale[v * DO + o] = sc;
    shift[v * DO + o] = beta[v * DO + o] - mu * sc;
}

// ---------------------------------------------------------------------------
// Kernel 2b: C0[u,o] = sum_v adj[u,v] * shift[v,o]. 64 blocks (u).
// ---------------------------------------------------------------------------
__global__ __launch_bounds__(128) void k_c0(const float* __restrict__ adj,
                                            const float* __restrict__ shift,
                                            float* __restrict__ C0) {
    const int o = threadIdx.x;
    const int u = blockIdx.x;
    float c0 = 0.f;
#pragma unroll
    for (int v = 0; v < VN; ++v)
        c0 += adj[u * VN + v] * shift[v * DO + o];
    C0[u * DO + o] = c0;
}

// ---------------------------------------------------------------------------
// Kernel 3 (MFMA mix): out[b,u,o] = relu( sum_v adj[u,v]*(h[b,v,o]*scale[v,o])
//                                         + C0[u,o] )
// Known-good R0/R1 version (~4.5 TB/s effective). Unchanged.
// ---------------------------------------------------------------------------
__global__ __launch_bounds__(512, 4) void k_mix(const unsigned short* __restrict__ h,
                                                const float* __restrict__ scale,
                                                const unsigned short* __restrict__ adjbf,
                                                const float* __restrict__ C0,
                                                float* __restrict__ out) {
    __shared__ unsigned short hsT[4][DO][72];   // 73,728 B
    const int t = threadIdx.x;
    const int b0 = blockIdx.x * 4;
    const int bt = b0 >> 7;
    const int r = b0 & 127;
    const int swm = r >> 6, srt = (r >> 4) & 3, squad = (r >> 2) & 3;

    // stage: 16 iters x 512 threads = 8192 (v,o) pairs, 8 B each
#pragma unroll
    for (int c = 0; c < 16; ++c) {
        const int p = c * 512 + t;
        const int v = p >> 7, o = p & 127;
        const size_t off = (size_t)(bt * 64 + v) * 16384
                         + (size_t)(((swm * 2 + (o >> 6)) * 4 + ((o >> 4) & 3)) * 4 + srt) * 256
                         + (size_t)(squad * 16 + (o & 15)) * 4;
        const uint2 pk = *(const uint2*)(h + off);
        const float sc = scale[v * DO + o];
        hsT[0][o][v] = f2bf(bf2f((unsigned short)(pk.x & 0xFFFF)) * sc);
        hsT[1][o][v] = f2bf(bf2f((unsigned short)(pk.x >> 16)) * sc);
        hsT[2][o][v] = f2bf(bf2f((unsigned short)(pk.y & 0xFFFF)) * sc);
        hsT[3][o][v] = f2bf(bf2f((unsigned short)(pk.y >> 16)) * sc);
    }
    __syncthreads();

    const int w = t >> 6, lane = t & 63;
    const int bl = w >> 1, nh = w & 1;
    const int quad = lane >> 4, l16 = lane & 15;
    const int b = b0 + bl;

    short8 af[4][2];
#pragma unroll
    for (int mt = 0; mt < 4; ++mt)
#pragma unroll
        for (int ks = 0; ks < 2; ++ks)
            af[mt][ks] = *(const short8*)(adjbf + (mt * 16 + l16) * VN
                                          + ks * 32 + quad * 8);

    f32x4 acc[4][4];
#pragma unroll
    for (int mt = 0; mt < 4; ++mt)
#pragma unroll
        for (int nt = 0; nt < 4; ++nt) acc[mt][nt] = (f32x4){0.f, 0.f, 0.f, 0.f};

#pragma unroll
    for (int nt = 0; nt < 4; ++nt) {
        const unsigned short* bp = &hsT[bl][nh * 64 + nt * 16 + l16][quad * 8];
        short8 bf0 = *(const short8*)(bp);
        short8 bf1 = *(const short8*)(bp + 32);
#pragma unroll
        for (int mt = 0; mt < 4; ++mt) {
            acc[mt][nt] = __builtin_amdgcn_mfma_f32_16x16x32_bf16(
                af[mt][0], bf0, acc[mt][nt], 0, 0, 0);
            acc[mt][nt] = __builtin_amdgcn_mfma_f32_16x16x32_bf16(
                af[mt][1], bf1, acc[mt][nt], 0, 0, 0);
        }
    }

#pragma unroll
    for (int mt = 0; mt < 4; ++mt)
#pragma unroll
        for (int nt = 0; nt < 4; ++nt) {
            const int o = nh * 64 + nt * 16 + l16;
#pragma unroll
            for (int e = 0; e < 4; ++e) {
                const int u = mt * 16 + quad * 4 + e;
                out[((size_t)b * VN + u) * DO + o] =
                    fmaxf(acc[mt][nt][e] + C0[u * DO + o], 0.0f);
            }
        }
}

// ---------------------------------------------------------------------------
extern "C" void kernel_launch(void* const* d_in, const int* in_sizes, int n_in,
                              void* d_out, int out_size, void* d_ws, size_t ws_size,
                              hipStream_t stream) {
    const float* feat  = (const float*)d_in[0];
    const float* adj   = (const float*)d_in[1];
    const float* W     = (const float*)d_in[2];
    const float* bias  = (const float*)d_in[3];
    const float* gamma = (const float*)d_in[4];
    const float* beta  = (const float*)d_in[5];
    float* out = (float*)d_out;

    char* ws = (char*)d_ws;
    unsigned short* h     = (unsigned short*)ws;                 // 67,108,864 B
    unsigned short* Wt    = (unsigned short*)(ws + 67108864ull); //  2,097,152 B
    unsigned short* adjbf = (unsigned short*)(ws + 69206016ull); //      8,192 B
    float* psA   = (float*)(ws + 69214208ull);                   //  2 MiB
    float* psB   = psA + 524288;                                 //  2 MiB
    float* scale = psB + 524288;                                 // 32 KiB
    float* shift = scale + 8192;                                 // 32 KiB
    float* C0    = shift + 8192;                                 // 32 KiB

    k_prep<<<dim3(513), dim3(256), 0, stream>>>(W, adj, Wt, adjbf);
    k_gemm1<<<dim3(64, 32), dim3(256), 0, stream>>>(feat, Wt, bias, h, psA, psB);
    k_reduce<<<dim3(64), dim3(128), 0, stream>>>(psA, psB, gamma, beta, scale, shift);
    k_c0<<<dim3(64), dim3(128), 0, stream>>>(adj, shift, C0);
    k_mix<<<dim3(1024), dim3(512), 0, stream>>>(h, scale, adjbf, C0, out);
}